// Round 9
// baseline (485.148 us; speedup 1.0000x reference)
//
#include <hip/hip_runtime.h>
#include <math.h>

#define NB 64      // batch
#define NCH 64     // channels C
#define NT 4096    // time
#define TOUT 512   // output timesteps per block
#define ROWS 768   // staged rows = TOUT + 256 halo (receptive field 255)

typedef float f32x4 __attribute__((ext_vector_type(4)));
typedef short s16x8 __attribute__((ext_vector_type(8)));

__device__ __forceinline__ float fast_rcp(float x) { return __builtin_amdgcn_rcpf(x); }
__device__ __forceinline__ float fast_sigmoid(float x) { return fast_rcp(1.0f + __expf(-x)); }
__device__ __forceinline__ float fast_tanh(float x) {
    return 1.0f - 2.0f * fast_rcp(__expf(2.0f * x) + 1.0f);
}
__device__ __forceinline__ unsigned short f2bf(float f) {   // RNE float->bf16
    unsigned int u = __builtin_bit_cast(unsigned int, f);
    u += 0x7fffu + ((u >> 16) & 1u);
    return (unsigned short)(u >> 16);
}
__device__ __forceinline__ float bf2f_lo(unsigned int u) { return __builtin_bit_cast(float, u << 16); }
__device__ __forceinline__ float bf2f_hi(unsigned int u) { return __builtin_bit_cast(float, u & 0xffff0000u); }

// swizzled LDS byte offset: row stride 128B, XOR bits 4-6 with row&7 (G4 fix)
#define HSW(j, cb) ((j)*128 + ((cb) ^ (((j)&7) << 4)))

// LDS map: hs [768x128B] @0 (96KB) | gbuf0 @98304 (16KB) | gbuf1 @114688 (16KB)
//          | w1buf @131072 (32KB).  xs and head-red overlay the gbuf region.
#define OFF_GB0 98304
#define OFF_GB1 114688
#define OFF_W   131072
#define LDS_SZ  163840

// -------- weight pre-pack: fragment-ordered bf16 --------
// w1p: [L][g4][mi2][ks4][lane64][8]  A[co][k], co=16g+(l&15)+64mi, k=32ks+8(l>>4)+j
//      k = ci + 64*tap  (ci=k&63, tap=k>>6; tap0 = t-d, tap1 = t)
// w2p: [L][g4][ks2][lane64][8]       A[co][ci], co=16g+(l&15), ci=32ks+8(l>>4)+j
__global__ __launch_bounds__(256) void k_pack(
    const float* __restrict__ bw1, const float* __restrict__ bw2,
    short* __restrict__ w1p, short* __restrict__ w2p)
{
    const int id = blockIdx.x * 256 + threadIdx.x;
    if (id < 16384) {
        const int l = id & 63, ks = (id >> 6) & 3, mi = (id >> 8) & 1,
                  g = (id >> 9) & 3, L = id >> 11;
        const int co = 16*g + (l & 15) + 64*mi;
        short v[8];
        #pragma unroll
        for (int j = 0; j < 8; ++j) {
            const int k = 32*ks + 8*(l >> 4) + j;
            const int ci = k & 63, tap = k >> 6;
            v[j] = (short)f2bf(bw1[((size_t)(L*128 + co)*64 + ci)*2 + tap]);
        }
        *(s16x8*)(w1p + (size_t)id*8) = *(const s16x8*)v;
    } else if (id < 16384 + 4096) {
        const int id2 = id - 16384;
        const int l = id2 & 63, ks = (id2 >> 6) & 1, g = (id2 >> 7) & 3, L = id2 >> 9;
        const int co = 16*g + (l & 15);
        short v[8];
        #pragma unroll
        for (int j = 0; j < 8; ++j) {
            const int ci = 32*ks + 8*(l >> 4) + j;
            v[j] = (short)f2bf(bw2[(size_t)(L*64 + co)*64 + ci]);
        }
        *(s16x8*)(w2p + (size_t)id2*8) = *(const s16x8*)v;
    }
}

// -------- head-weight composition: Wc[64][10] (1/9 folded), bc[10] --------
__global__ void k_compose(
    const float* __restrict__ w_mid, const float* __restrict__ b_mid,
    const float* __restrict__ w_pi,  const float* __restrict__ b_pi,
    const float* __restrict__ w_mu,  const float* __restrict__ b_mu,
    const float* __restrict__ w_sg,  const float* __restrict__ b_sg,
    float* __restrict__ wct, float* __restrict__ bc)
{
    const int tid = threadIdx.x;
    if (tid < 640) {
        const int o = tid >> 6, c = tid & 63;
        const float* wh = (o < 4) ? (w_pi + o*128)
                        : (o < 7) ? (w_mu + (o-4)*128) : (w_sg + (o-7)*128);
        float s = 0.f;
        for (int j = 0; j < 128; ++j) s += wh[j] * w_mid[j*64 + c];
        wct[c*10 + o] = s * (1.0f/9.0f);
    }
    if (tid < 10) {
        const int o = tid;
        const float* wh = (o < 4) ? (w_pi + o*128)
                        : (o < 7) ? (w_mu + (o-4)*128) : (w_sg + (o-7)*128);
        const float bh = (o < 4) ? b_pi[o] : (o < 7) ? b_mu[o-4] : b_sg[o-7];
        float s = bh;
        for (int j = 0; j < 128; ++j) s += wh[j] * b_mid[j];
        bc[o] = s;
    }
}

// One 128-t chunk of one layer. 16 waves: wave=(cg=w&3 channel grp, th=w>>2
// t-quarter), 2 nf-tiles each. gbuf double-buffered -> single mid-barrier.
// In-place hs safe: chunk reads rows [TC-d, TC+127], later (lower) chunks
// write [TC',TC'+128) with TC'<TC; own-row write ordered by the mid-barrier.
// ZERO-PAD: rows with global t<0 (t0+r<256) written as exact 0.
#define CHUNK_BODY(TC, USEREG, CC)                                              \
  {                                                                             \
    const int gof = gsel ? OFF_GB1 : OFF_GB0;                                   \
    f32x4 acg0[2], acg1[2];                                                     \
    acg0[0] = (f32x4){0.f,0.f,0.f,0.f}; acg0[1] = (f32x4){0.f,0.f,0.f,0.f};     \
    acg1[0] = (f32x4){0.f,0.f,0.f,0.f}; acg1[1] = (f32x4){0.f,0.f,0.f,0.f};     \
    _Pragma("unroll")                                                           \
    for (int ks = 0; ks < 4; ++ks) {                                            \
      const s16x8 a10 = *(const s16x8*)(lds + OFF_W + (size_t)(((cg*2+0)*4+ks)*64 + l)*16); \
      const s16x8 a11 = *(const s16x8*)(lds + OFF_W + (size_t)(((cg*2+1)*4+ks)*64 + l)*16); \
      _Pragma("unroll")                                                         \
      for (int nf = 0; nf < 2; ++nf) {                                          \
        const int rb = (TC) + 32*th + 16*nf + l15;                              \
        int jr = rb - d + (ks >> 1)*d;   /* tap0: r-d, tap1: r */               \
        jr = jr < 0 ? 0 : jr;            /* garbage-region clamp (finite) */    \
        const int cb = 64*(ks & 1) + 16*lq;                                     \
        const s16x8 bf = *(const s16x8*)(lds + HSW(jr, cb));                    \
        acg0[nf] = __builtin_amdgcn_mfma_f32_16x16x32_bf16(a10, bf, acg0[nf], 0,0,0); \
        acg1[nf] = __builtin_amdgcn_mfma_f32_16x16x32_bf16(a11, bf, acg1[nf], 0,0,0); \
      }                                                                         \
    }                                                                           \
    _Pragma("unroll")                                                           \
    for (int nf = 0; nf < 2; ++nf) {                                            \
      const int tl = 32*th + 16*nf + l15;                                       \
      unsigned short gg[4];                                                     \
      _Pragma("unroll")                                                         \
      for (int rr = 0; rr < 4; ++rr)                                            \
        gg[rr] = f2bf(fast_tanh(acg0[nf][rr] + bt[rr]) *                        \
                      fast_sigmoid(acg1[nf][rr] + bs[rr]));                     \
      uint2 pk;                                                                 \
      pk.x = (unsigned int)gg[0] | ((unsigned int)gg[1] << 16);                 \
      pk.y = (unsigned int)gg[2] | ((unsigned int)gg[3] << 16);                 \
      *(uint2*)(lds + gof + HSW(tl, 2*cobase)) = pk;                            \
    }                                                                           \
    __syncthreads();                                                            \
    f32x4 c2[2];                                                                \
    c2[0] = (f32x4){0.f,0.f,0.f,0.f}; c2[1] = (f32x4){0.f,0.f,0.f,0.f};         \
    _Pragma("unroll")                                                           \
    for (int ks = 0; ks < 2; ++ks) {                                            \
      _Pragma("unroll")                                                         \
      for (int nf = 0; nf < 2; ++nf) {                                          \
        const int tl = 32*th + 16*nf + l15;                                     \
        const int cb = 64*ks + 16*lq;                                           \
        const s16x8 bf = *(const s16x8*)(lds + gof + HSW(tl, cb));              \
        c2[nf] = __builtin_amdgcn_mfma_f32_16x16x32_bf16(a2[ks], bf, c2[nf], 0,0,0); \
      }                                                                         \
    }                                                                           \
    _Pragma("unroll")                                                           \
    for (int nf = 0; nf < 2; ++nf) {                                            \
      const int r  = (TC) + 32*th + 16*nf + l15;                                \
      const int ha = HSW(r, 2*cobase);                                          \
      f32x4 resid;                                                              \
      if (USEREG) {                                                             \
        resid = h_reg[CC][nf];                                                  \
      } else {                                                                  \
        const uint2 hp = *(const uint2*)(lds + ha);                             \
        resid[0] = bf2f_lo(hp.x); resid[1] = bf2f_hi(hp.x);                     \
        resid[2] = bf2f_lo(hp.y); resid[3] = bf2f_hi(hp.y);                     \
      }                                                                         \
      f32x4 hn;                                                                 \
      _Pragma("unroll")                                                         \
      for (int rr = 0; rr < 4; ++rr) hn[rr] = c2[nf][rr] + b2v[rr] + resid[rr]; \
      if (USEREG) {                                                             \
        h_reg[CC][nf] = hn;                                                     \
        _Pragma("unroll")                                                       \
        for (int rr = 0; rr < 4; ++rr) acc_reg[CC][nf][rr] += hn[rr];           \
      }                                                                         \
      uint2 po;                                                                 \
      po.x = (unsigned int)f2bf(hn[0]) | ((unsigned int)f2bf(hn[1]) << 16);     \
      po.y = (unsigned int)f2bf(hn[2]) | ((unsigned int)f2bf(hn[3]) << 16);     \
      if (t0 + r < 256) { po.x = 0u; po.y = 0u; }  /* preserve causal zero-pad */ \
      *(uint2*)(lds + ha) = po;                                                 \
    }                                                                           \
    gsel ^= 1;                                                                  \
  }

// -------- mega kernel: input conv + 8 gated residual layers + head --------
// amdgpu_waves_per_eu(4,4): LDS (160KB) already limits to 1 WG/CU = 4 waves/EU;
// pinning MAX=4 stops the allocator from targeting 8 waves/EU (=64 VGPR, which
// spilled ~815 MB/dispatch in rounds 7-8) and frees the full 128-VGPR budget.
__global__ __launch_bounds__(1024) __attribute__((amdgpu_waves_per_eu(4, 4)))
void k_mega(
    const short* __restrict__ w1p, const float* __restrict__ bb1,
    const short* __restrict__ w2p, const float* __restrict__ bb2,
    const float* __restrict__ w_in, const float* __restrict__ b_in,
    const float* __restrict__ x,
    const float* __restrict__ wct, const float* __restrict__ bc,
    float* __restrict__ out)
{
    __shared__ __align__(16) unsigned char lds[LDS_SZ];
    const int b   = blockIdx.x;
    const int t0  = blockIdx.y * TOUT;
    const int tid = threadIdx.x;
    const int w   = tid >> 6;          // 16 waves
    const int l   = tid & 63;
    const int l15 = l & 15, lq = l >> 4;
    const int cg  = w & 3;             // channel group (16 out-ch)
    const int th  = w >> 2;            // t-quarter of a 128-row chunk
    const int cobase = 16*cg + 4*lq;   // C/D frag rows: cobase + rr
    const float inv = 1.0f / 4095.0f;
    int gsel = 0;

    // ---- stage xs[769] = x[t0-257 .. t0+511] (zeros left of 0) ----
    float* xs = (float*)(lds + OFF_GB0);
    if (tid < ROWS + 1) {
        const int t = t0 - 257 + tid;
        xs[tid] = (t >= 0) ? x[(size_t)b*NT + t] : 0.f;
    }
    __syncthreads();

    // ---- h0 (input conv) into hs bf16, all 768 rows; 2 channel pairs/wave ----
    #pragma unroll
    for (int pp = 0; pp < 2; ++pp) {
        const int cp = w*2 + pp, c0 = 2*cp;
        const float wa0=w_in[c0*4+0], wa1=w_in[c0*4+1], wa2=w_in[c0*4+2], wa3=w_in[c0*4+3], ba=b_in[c0];
        const float wb0=w_in[c0*4+4], wb1=w_in[c0*4+5], wb2=w_in[c0*4+6], wb3=w_in[c0*4+7], bb=b_in[c0+1];
        for (int j = l; j < ROWS; j += 64) {
            const int t = t0 - 256 + j;
            float v0 = 0.f, v1 = 0.f;
            if (t >= 0) {
                const float x1v = xs[j+1], x0v = xs[j];
                const float l1v = (float)t * inv;
                const float l0v = (t > 0) ? (float)(t-1)*inv : 0.f;
                v0 = ba + wa0*x0v + wa1*x1v + wa2*l0v + wa3*l1v;
                v1 = bb + wb0*x0v + wb1*x1v + wb2*l0v + wb3*l1v;
            }
            *(unsigned int*)(lds + HSW(j, 4*cp)) =
                (unsigned int)f2bf(v0) | ((unsigned int)f2bf(v1) << 16);
        }
    }

    // ---- fp32 h/acc registers for this thread's output fragments ----
    f32x4 h_reg[4][2], acc_reg[4][2];
    {
        float wi0[4], wi1[4], wi2[4], wi3[4], bi[4];
        #pragma unroll
        for (int rr = 0; rr < 4; ++rr) {
            const int co = cobase + rr;
            wi0[rr]=w_in[co*4+0]; wi1[rr]=w_in[co*4+1];
            wi2[rr]=w_in[co*4+2]; wi3[rr]=w_in[co*4+3]; bi[rr]=b_in[co];
        }
        #pragma unroll
        for (int cc = 0; cc < 4; ++cc) {
            #pragma unroll
            for (int nf = 0; nf < 2; ++nf) {
                const int j = 256 + 128*cc + 32*th + 16*nf + l15;
                const int t = t0 - 256 + j;          // >= 0 always
                const float x1v = xs[j+1], x0v = xs[j];
                const float l1v = (float)t * inv;
                const float l0v = (t > 0) ? (float)(t-1)*inv : 0.f;
                f32x4 hv;
                #pragma unroll
                for (int rr = 0; rr < 4; ++rr)
                    hv[rr] = bi[rr] + wi0[rr]*x0v + wi1[rr]*x1v + wi2[rr]*l0v + wi3[rr]*l1v;
                h_reg[cc][nf] = hv;
                acc_reg[cc][nf] = hv;                // acc tap 0 = h0
            }
        }
    }
    __syncthreads();   // hs complete; xs region free for gbuf

    // ---- 8 layers, in-place in hs, chunks high-to-low, 1 barrier/chunk ----
    for (int li = 0; li < 8; ++li) {
        const int d = 1 << li;
        // stage this layer's w1 into LDS (all prior w1buf reads done: every
        // wave passed the last chunk's mid-barrier, which follows its phase1)
        {
            const s16x8* src = (const s16x8*)(w1p + (size_t)li*16384);
            s16x8* dst = (s16x8*)(lds + OFF_W);
            for (int i = tid; i < 2048; i += 1024) dst[i] = src[i];
        }
        s16x8 a2[2];
        #pragma unroll
        for (int ks = 0; ks < 2; ++ks)
            a2[ks] = *(const s16x8*)(w2p + (size_t)li*4096 + (size_t)((cg*2 + ks)*64 + l)*8);
        float bt[4], bs[4], b2v[4];
        #pragma unroll
        for (int rr = 0; rr < 4; ++rr) {
            bt[rr]  = bb1[li*128 + cobase + rr];
            bs[rr]  = bb1[li*128 + 64 + cobase + rr];
            b2v[rr] = bb2[li*64 + cobase + rr];
        }
        __syncthreads();   // w1 staged; also orders prev-layer hs writes vs reads

        // output chunks (register residual), high base first
        #pragma unroll
        for (int cci = 0; cci < 4; ++cci) {
            const int cc = 3 - cci;
            CHUNK_BODY(256 + 128*cc, 1, cc)
        }
        // halo chunks (bf16 LDS residual); sub-validity rows garbage-but-finite
        if (li < 7) CHUNK_BODY(128, 0, 0)
        if (li < 6) CHUNK_BODY(0,   0, 0)
    }

    // ---- fused head: out = nonlin(Wc @ relu(acc) + bc) ----
    __syncthreads();   // all gbuf reads done; region becomes red
    float* red = (float*)(lds + OFF_GB0);   // [cg4][t128][10] = 20480 B
    #pragma unroll
    for (int cc = 0; cc < 4; ++cc) {
        #pragma unroll
        for (int nf = 0; nf < 2; ++nf) {
            float p[10];
            #pragma unroll
            for (int o = 0; o < 10; ++o) p[o] = 0.f;
            #pragma unroll
            for (int rr = 0; rr < 4; ++rr) {
                float a = acc_reg[cc][nf][rr];
                a = a > 0.f ? a : 0.f;
                const float* wr = wct + (cobase + rr)*10;   // L2-hot
                #pragma unroll
                for (int o = 0; o < 10; ++o) p[o] += wr[o] * a;
            }
            #pragma unroll
            for (int o = 0; o < 10; ++o) {      // reduce over lq (4 lanes)
                p[o] += __shfl_xor(p[o], 16, 64);
                p[o] += __shfl_xor(p[o], 32, 64);
            }
            if (lq == 0) {
                const int tl = 32*th + 16*nf + l15;
                #pragma unroll
                for (int o = 0; o < 10; ++o) red[(cg*128 + tl)*10 + o] = p[o];
            }
        }
        __syncthreads();
        if (tid < 128) {
            float hd[10];
            #pragma unroll
            for (int o = 0; o < 10; ++o)
                hd[o] = bc[o] + red[(0*128+tid)*10+o] + red[(1*128+tid)*10+o]
                              + red[(2*128+tid)*10+o] + red[(3*128+tid)*10+o];
            const int t = t0 + 128*cc + tid;
            const float m  = fmaxf(fmaxf(hd[0], hd[1]), fmaxf(hd[2], hd[3]));
            const float e0 = __expf(hd[0]-m), e1 = __expf(hd[1]-m);
            const float e2 = __expf(hd[2]-m), e3 = __expf(hd[3]-m);
            const float rs = fast_rcp(e0+e1+e2+e3);
            const size_t piBase = (size_t)(b*4)*NT + t;
            out[piBase       ] = e0*rs;
            out[piBase +  NT ] = e1*rs;
            out[piBase + 2*NT] = e2*rs;
            out[piBase + 3*NT] = e3*rs;
            float* muO = out + (size_t)NB*4*NT;
            float* sgO = out + (size_t)NB*7*NT;
            #pragma unroll
            for (int o = 0; o < 3; ++o) {
                muO[(size_t)(b*3+o)*NT + t] = 2.0f * fast_tanh(0.5f * hd[4+o]);
                const float sv = hd[7+o];
                sgO[(size_t)(b*3+o)*NT + t] = (sv > 15.0f) ? sv : logf(1.0f + __expf(sv));
            }
        }
        __syncthreads();
    }
}

extern "C" void kernel_launch(void* const* d_in, const int* in_sizes, int n_in,
                              void* d_out, int out_size, void* d_ws, size_t ws_size,
                              hipStream_t stream)
{
    const float* x     = (const float*)d_in[0];
    const float* w_in  = (const float*)d_in[1];
    const float* b_in  = (const float*)d_in[2];
    const float* bw1   = (const float*)d_in[3];   // [8][128][64][2]
    const float* bb1   = (const float*)d_in[4];   // [8][128]
    const float* bw2   = (const float*)d_in[5];   // [8][64][64][1]
    const float* bb2   = (const float*)d_in[6];   // [8][64]
    const float* w_mid = (const float*)d_in[7];
    const float* b_mid = (const float*)d_in[8];
    const float* w_pi  = (const float*)d_in[9];
    const float* b_pi  = (const float*)d_in[10];
    const float* w_mu  = (const float*)d_in[11];
    const float* b_mu  = (const float*)d_in[12];
    const float* w_sg  = (const float*)d_in[13];
    const float* b_sg  = (const float*)d_in[14];
    float* out = (float*)d_out;

    short* w1p = (short*)d_ws;                    // 262144 B
    short* w2p = w1p + 8*16384;                   // 65536 B
    float* wct = (float*)(w2p + 8*4096);          // 640 floats
    float* bcp = wct + 640;                       // 10 floats

    k_pack<<<80, 256, 0, stream>>>(bw1, bw2, w1p, w2p);
    k_compose<<<1, 1024, 0, stream>>>(w_mid, b_mid, w_pi, b_pi, w_mu, b_mu,
                                      w_sg, b_sg, wct, bcp);
    k_mega<<<dim3(NB, NT/TOUT), 1024, 0, stream>>>(
        w1p, bb1, w2p, bb2, w_in, b_in, x, wct, bcp, out);
}

// Round 10
// 417.302 us; speedup vs baseline: 1.1626x; 1.1626x over previous
//
#include <hip/hip_runtime.h>
#include <math.h>

#define NB 64      // batch
#define NCH 64     // channels C
#define NT 4096    // time
#define TOUT 256   // output timesteps per block
#define ROWS 512   // staged rows = TOUT + 256 halo (receptive field 255)

typedef float f32x4 __attribute__((ext_vector_type(4)));
typedef short s16x8 __attribute__((ext_vector_type(8)));

__device__ __forceinline__ float fast_rcp(float x) { return __builtin_amdgcn_rcpf(x); }
__device__ __forceinline__ float fast_sigmoid(float x) { return fast_rcp(1.0f + __expf(-x)); }
__device__ __forceinline__ float fast_tanh(float x) {
    return 1.0f - 2.0f * fast_rcp(__expf(2.0f * x) + 1.0f);
}
__device__ __forceinline__ unsigned short f2bf(float f) {   // RNE float->bf16
    unsigned int u = __builtin_bit_cast(unsigned int, f);
    u += 0x7fffu + ((u >> 16) & 1u);
    return (unsigned short)(u >> 16);
}
__device__ __forceinline__ float bf2f_lo(unsigned int u) { return __builtin_bit_cast(float, u << 16); }
__device__ __forceinline__ float bf2f_hi(unsigned int u) { return __builtin_bit_cast(float, u & 0xffff0000u); }

// swizzled LDS byte offset: row stride 128B, XOR bits 4-6 with row&7 (G4 fix)
#define HSW(j, cb) ((j)*128 + ((cb) ^ (((j)&7) << 4)))

// LDS map: hs [512x128B] @0 (64KB) | gbuf @65536 (16KB).
// xs overlays gbuf; head-red overlays hs. Total 81920 B -> 2 blocks/CU.
#define OFF_GB  65536
#define LDS_SZ  81920

// -------- weight pre-pack: fragment-ordered bf16 --------
// w1p: [L][g4][mi2][ks4][lane64][8]  A[co][k], co=16g+(l&15)+64mi, k=32ks+8(l>>4)+j
//      k = ci + 64*tap  (ci=k&63, tap=k>>6; tap0 = t-d, tap1 = t)
// w2p: [L][g4][ks2][lane64][8]       A[co][ci], co=16g+(l&15), ci=32ks+8(l>>4)+j
__global__ __launch_bounds__(256) void k_pack(
    const float* __restrict__ bw1, const float* __restrict__ bw2,
    short* __restrict__ w1p, short* __restrict__ w2p)
{
    const int id = blockIdx.x * 256 + threadIdx.x;
    if (id < 16384) {
        const int l = id & 63, ks = (id >> 6) & 3, mi = (id >> 8) & 1,
                  g = (id >> 9) & 3, L = id >> 11;
        const int co = 16*g + (l & 15) + 64*mi;
        short v[8];
        #pragma unroll
        for (int j = 0; j < 8; ++j) {
            const int k = 32*ks + 8*(l >> 4) + j;
            const int ci = k & 63, tap = k >> 6;
            v[j] = (short)f2bf(bw1[((size_t)(L*128 + co)*64 + ci)*2 + tap]);
        }
        *(s16x8*)(w1p + (size_t)id*8) = *(const s16x8*)v;
    } else if (id < 16384 + 4096) {
        const int id2 = id - 16384;
        const int l = id2 & 63, ks = (id2 >> 6) & 1, g = (id2 >> 7) & 3, L = id2 >> 9;
        const int co = 16*g + (l & 15);
        short v[8];
        #pragma unroll
        for (int j = 0; j < 8; ++j) {
            const int ci = 32*ks + 8*(l >> 4) + j;
            v[j] = (short)f2bf(bw2[(size_t)(L*64 + co)*64 + ci]);
        }
        *(s16x8*)(w2p + (size_t)id2*8) = *(const s16x8*)v;
    }
}

// -------- head-weight composition: Wc[64][10] (1/9 folded), bc[10] --------
__global__ void k_compose(
    const float* __restrict__ w_mid, const float* __restrict__ b_mid,
    const float* __restrict__ w_pi,  const float* __restrict__ b_pi,
    const float* __restrict__ w_mu,  const float* __restrict__ b_mu,
    const float* __restrict__ w_sg,  const float* __restrict__ b_sg,
    float* __restrict__ wct, float* __restrict__ bc)
{
    const int tid = threadIdx.x;
    if (tid < 640) {
        const int o = tid >> 6, c = tid & 63;
        const float* wh = (o < 4) ? (w_pi + o*128)
                        : (o < 7) ? (w_mu + (o-4)*128) : (w_sg + (o-7)*128);
        float s = 0.f;
        for (int j = 0; j < 128; ++j) s += wh[j] * w_mid[j*64 + c];
        wct[c*10 + o] = s * (1.0f/9.0f);
    }
    if (tid < 10) {
        const int o = tid;
        const float* wh = (o < 4) ? (w_pi + o*128)
                        : (o < 7) ? (w_mu + (o-4)*128) : (w_sg + (o-7)*128);
        const float bh = (o < 4) ? b_pi[o] : (o < 7) ? b_mu[o-4] : b_sg[o-7];
        float s = bh;
        for (int j = 0; j < 128; ++j) s += wh[j] * b_mid[j];
        bc[o] = s;
    }
}

// One 128-t chunk of one layer. 8 waves: wave=(cg=w&3 channel grp, th=w>>2
// t-half), 4 nf-tiles each. Single gbuf -> two barriers per chunk:
//   ph1 -> gate(regs) -> barA (prev ph2 gbuf reads done) -> gwrite
//   -> barB (gbuf ready) -> ph2 -> epilogue (hs write).
// In-place hs safe: chunk k+1 (lower TC) reads rows < TC; epilogue writes
// [TC,TC+128) ordered after all same-chunk ph1 reads by barA+barB.
// ZERO-PAD: rows with global t<0 (t0+r<256) written as exact 0.
#define CHUNK_BODY(TC, USEREG, CC)                                              \
  {                                                                             \
    f32x4 accf0[4], accf1[4];                                                   \
    _Pragma("unroll")                                                           \
    for (int nf = 0; nf < 4; ++nf) {                                            \
      accf0[nf] = (f32x4){0.f,0.f,0.f,0.f};                                     \
      accf1[nf] = (f32x4){0.f,0.f,0.f,0.f};                                     \
    }                                                                           \
    _Pragma("unroll")                                                           \
    for (int nf = 0; nf < 4; ++nf) {                                            \
      const int rb = (TC) + 64*th + 16*nf + l15;                                \
      _Pragma("unroll")                                                         \
      for (int ks = 0; ks < 4; ++ks) {                                          \
        int jr = rb - d + (ks >> 1)*d;   /* tap0: r-d, tap1: r */               \
        jr = jr < 0 ? 0 : jr;            /* garbage-region clamp (finite) */    \
        const int cb = 64*(ks & 1) + 16*lq;                                     \
        const s16x8 bf = *(const s16x8*)(lds + HSW(jr, cb));                    \
        accf0[nf] = __builtin_amdgcn_mfma_f32_16x16x32_bf16(a1[0][ks], bf, accf0[nf], 0,0,0); \
        accf1[nf] = __builtin_amdgcn_mfma_f32_16x16x32_bf16(a1[1][ks], bf, accf1[nf], 0,0,0); \
      }                                                                         \
    }                                                                           \
    uint2 gpk[4];                                                               \
    _Pragma("unroll")                                                           \
    for (int nf = 0; nf < 4; ++nf) {                                            \
      unsigned short gg[4];                                                     \
      _Pragma("unroll")                                                         \
      for (int rr = 0; rr < 4; ++rr)                                            \
        gg[rr] = f2bf(fast_tanh(accf0[nf][rr] + bt[rr]) *                       \
                      fast_sigmoid(accf1[nf][rr] + bs[rr]));                    \
      gpk[nf].x = (unsigned int)gg[0] | ((unsigned int)gg[1] << 16);            \
      gpk[nf].y = (unsigned int)gg[2] | ((unsigned int)gg[3] << 16);            \
    }                                                                           \
    __syncthreads();   /* barA: prev chunk's gbuf reads complete */             \
    _Pragma("unroll")                                                           \
    for (int nf = 0; nf < 4; ++nf) {                                            \
      const int tl = 64*th + 16*nf + l15;                                       \
      *(uint2*)(lds + OFF_GB + HSW(tl, 2*cobase)) = gpk[nf];                    \
    }                                                                           \
    __syncthreads();   /* barB: gbuf fully written */                           \
    f32x4 c2[4];                                                                \
    _Pragma("unroll")                                                           \
    for (int nf = 0; nf < 4; ++nf) c2[nf] = (f32x4){0.f,0.f,0.f,0.f};           \
    _Pragma("unroll")                                                           \
    for (int nf = 0; nf < 4; ++nf) {                                            \
      const int tl = 64*th + 16*nf + l15;                                       \
      _Pragma("unroll")                                                         \
      for (int ks = 0; ks < 2; ++ks) {                                          \
        const int cb = 64*ks + 16*lq;                                           \
        const s16x8 bf = *(const s16x8*)(lds + OFF_GB + HSW(tl, cb));           \
        c2[nf] = __builtin_amdgcn_mfma_f32_16x16x32_bf16(a2[ks], bf, c2[nf], 0,0,0); \
      }                                                                         \
    }                                                                           \
    _Pragma("unroll")                                                           \
    for (int nf = 0; nf < 4; ++nf) {                                            \
      const int r  = (TC) + 64*th + 16*nf + l15;                                \
      const int ha = HSW(r, 2*cobase);                                          \
      f32x4 resid;                                                              \
      if (USEREG) {                                                             \
        resid = h_reg[CC][nf];                                                  \
      } else {                                                                  \
        const uint2 hp = *(const uint2*)(lds + ha);                             \
        resid[0] = bf2f_lo(hp.x); resid[1] = bf2f_hi(hp.x);                     \
        resid[2] = bf2f_lo(hp.y); resid[3] = bf2f_hi(hp.y);                     \
      }                                                                         \
      f32x4 hn;                                                                 \
      _Pragma("unroll")                                                         \
      for (int rr = 0; rr < 4; ++rr) hn[rr] = c2[nf][rr] + b2v[rr] + resid[rr]; \
      if (USEREG) {                                                             \
        h_reg[CC][nf] = hn;                                                     \
        _Pragma("unroll")                                                       \
        for (int rr = 0; rr < 4; ++rr) acc_reg[CC][nf][rr] += hn[rr];           \
      }                                                                         \
      uint2 po;                                                                 \
      po.x = (unsigned int)f2bf(hn[0]) | ((unsigned int)f2bf(hn[1]) << 16);     \
      po.y = (unsigned int)f2bf(hn[2]) | ((unsigned int)f2bf(hn[3]) << 16);     \
      if (t0 + r < 256) { po.x = 0u; po.y = 0u; }  /* preserve causal zero-pad */ \
      *(uint2*)(lds + ha) = po;                                                 \
    }                                                                           \
  }

// -------- mega kernel: input conv + 8 gated residual layers + head --------
// 512 thr / 80KB LDS: 2 blocks/CU = 4 waves/EU; (512,2) gave VGPR=128 in R6.
__global__ __launch_bounds__(512, 2) void k_mega(
    const short* __restrict__ w1p, const float* __restrict__ bb1,
    const short* __restrict__ w2p, const float* __restrict__ bb2,
    const float* __restrict__ w_in, const float* __restrict__ b_in,
    const float* __restrict__ x,
    const float* __restrict__ wct, const float* __restrict__ bc,
    float* __restrict__ out)
{
    __shared__ __align__(16) unsigned char lds[LDS_SZ];
    const int b   = blockIdx.x;
    const int t0  = blockIdx.y * TOUT;
    const int tid = threadIdx.x;
    const int w   = tid >> 6;          // 8 waves
    const int l   = tid & 63;
    const int l15 = l & 15, lq = l >> 4;
    const int cg  = w & 3;             // channel group (16 out-ch)
    const int th  = w >> 2;            // t-half of a 128-row chunk
    const int cobase = 16*cg + 4*lq;   // C/D frag rows: cobase + rr
    const float inv = 1.0f / 4095.0f;

    // ---- stage xs[513] = x[t0-257 .. t0+255] (zeros left of 0) ----
    float* xs = (float*)(lds + OFF_GB);
    for (int idx = tid; idx < ROWS + 1; idx += 512) {
        const int t = t0 - 257 + idx;
        xs[idx] = (t >= 0) ? x[(size_t)b*NT + t] : 0.f;
    }
    __syncthreads();

    // ---- h0 (input conv) into hs bf16, all 512 rows; 4 channel pairs/wave ----
    #pragma unroll
    for (int pp = 0; pp < 4; ++pp) {
        const int cp = w*4 + pp, c0 = 2*cp;
        const float wa0=w_in[c0*4+0], wa1=w_in[c0*4+1], wa2=w_in[c0*4+2], wa3=w_in[c0*4+3], ba=b_in[c0];
        const float wb0=w_in[c0*4+4], wb1=w_in[c0*4+5], wb2=w_in[c0*4+6], wb3=w_in[c0*4+7], bb=b_in[c0+1];
        for (int j = l; j < ROWS; j += 64) {
            const int t = t0 - 256 + j;
            float v0 = 0.f, v1 = 0.f;
            if (t >= 0) {
                const float x1v = xs[j+1], x0v = xs[j];
                const float l1v = (float)t * inv;
                const float l0v = (t > 0) ? (float)(t-1)*inv : 0.f;
                v0 = ba + wa0*x0v + wa1*x1v + wa2*l0v + wa3*l1v;
                v1 = bb + wb0*x0v + wb1*x1v + wb2*l0v + wb3*l1v;
            }
            *(unsigned int*)(lds + HSW(j, 4*cp)) =
                (unsigned int)f2bf(v0) | ((unsigned int)f2bf(v1) << 16);
        }
    }

    // ---- fp32 h/acc registers for this thread's output fragments ----
    f32x4 h_reg[2][4], acc_reg[2][4];
    {
        float wi0[4], wi1[4], wi2[4], wi3[4], bi[4];
        #pragma unroll
        for (int rr = 0; rr < 4; ++rr) {
            const int co = cobase + rr;
            wi0[rr]=w_in[co*4+0]; wi1[rr]=w_in[co*4+1];
            wi2[rr]=w_in[co*4+2]; wi3[rr]=w_in[co*4+3]; bi[rr]=b_in[co];
        }
        #pragma unroll
        for (int cc = 0; cc < 2; ++cc) {
            #pragma unroll
            for (int nf = 0; nf < 4; ++nf) {
                const int j = 256 + 128*cc + 64*th + 16*nf + l15;
                const int t = t0 - 256 + j;          // >= 0 always
                const float x1v = xs[j+1], x0v = xs[j];
                const float l1v = (float)t * inv;
                const float l0v = (t > 0) ? (float)(t-1)*inv : 0.f;
                f32x4 hv;
                #pragma unroll
                for (int rr = 0; rr < 4; ++rr)
                    hv[rr] = bi[rr] + wi0[rr]*x0v + wi1[rr]*x1v + wi2[rr]*l0v + wi3[rr]*l1v;
                h_reg[cc][nf] = hv;
                acc_reg[cc][nf] = hv;                // acc tap 0 = h0
            }
        }
    }
    __syncthreads();   // hs complete; xs region free for gbuf

    // ---- 8 layers, in-place in hs, chunks high-to-low ----
    for (int li = 0; li < 8; ++li) {
        const int d = 1 << li;
        const short* w1l = w1p + li*16384;
        const short* w2l = w2p + li*4096;
        s16x8 a1[2][4], a2[2];
        #pragma unroll
        for (int mi = 0; mi < 2; ++mi)
            #pragma unroll
            for (int ks = 0; ks < 4; ++ks)
                a1[mi][ks] = *(const s16x8*)(w1l + (size_t)(((cg*2 + mi)*4 + ks)*64 + l)*8);
        #pragma unroll
        for (int ks = 0; ks < 2; ++ks)
            a2[ks] = *(const s16x8*)(w2l + (size_t)((cg*2 + ks)*64 + l)*8);
        float bt[4], bs[4], b2v[4];
        #pragma unroll
        for (int rr = 0; rr < 4; ++rr) {
            bt[rr]  = bb1[li*128 + cobase + rr];
            bs[rr]  = bb1[li*128 + 64 + cobase + rr];
            b2v[rr] = bb2[li*64 + cobase + rr];
        }
        __syncthreads();   // orders prev-layer hs epilogue writes vs this layer's ph1 reads

        // output chunks (register residual), high base first
        #pragma unroll
        for (int cci = 0; cci < 2; ++cci) {
            const int cc = 1 - cci;
            CHUNK_BODY(256 + 128*cc, 1, cc)
        }
        // halo chunks (bf16 LDS residual); sub-validity rows garbage-but-finite
        if (li < 7) CHUNK_BODY(128, 0, 0)
        if (li < 6) CHUNK_BODY(0,   0, 0)
    }

    // ---- fused head: out = nonlin(Wc @ relu(acc) + bc) ----
    __syncthreads();   // all hs/gbuf accesses done; hs region becomes red
    float* red = (float*)lds;   // [cg4][t128][10] = 20480 B (overlays hs)
    #pragma unroll
    for (int cc = 0; cc < 2; ++cc) {
        #pragma unroll
        for (int nf = 0; nf < 4; ++nf) {
            float p[10];
            #pragma unroll
            for (int o = 0; o < 10; ++o) p[o] = 0.f;
            #pragma unroll
            for (int rr = 0; rr < 4; ++rr) {
                float a = acc_reg[cc][nf][rr];
                a = a > 0.f ? a : 0.f;
                const float* wr = wct + (cobase + rr)*10;   // L2-hot
                #pragma unroll
                for (int o = 0; o < 10; ++o) p[o] += wr[o] * a;
            }
            #pragma unroll
            for (int o = 0; o < 10; ++o) {      // reduce over lq (4 lanes)
                p[o] += __shfl_xor(p[o], 16, 64);
                p[o] += __shfl_xor(p[o], 32, 64);
            }
            if (lq == 0) {
                const int tl = 64*th + 16*nf + l15;
                #pragma unroll
                for (int o = 0; o < 10; ++o) red[(cg*128 + tl)*10 + o] = p[o];
            }
        }
        __syncthreads();
        if (tid < 128) {
            float hd[10];
            #pragma unroll
            for (int o = 0; o < 10; ++o)
                hd[o] = bc[o] + red[(0*128+tid)*10+o] + red[(1*128+tid)*10+o]
                              + red[(2*128+tid)*10+o] + red[(3*128+tid)*10+o];
            const int t = t0 + 128*cc + tid;
            const float m  = fmaxf(fmaxf(hd[0], hd[1]), fmaxf(hd[2], hd[3]));
            const float e0 = __expf(hd[0]-m), e1 = __expf(hd[1]-m);
            const float e2 = __expf(hd[2]-m), e3 = __expf(hd[3]-m);
            const float rs = fast_rcp(e0+e1+e2+e3);
            const size_t piBase = (size_t)(b*4)*NT + t;
            out[piBase       ] = e0*rs;
            out[piBase +  NT ] = e1*rs;
            out[piBase + 2*NT] = e2*rs;
            out[piBase + 3*NT] = e3*rs;
            float* muO = out + (size_t)NB*4*NT;
            float* sgO = out + (size_t)NB*7*NT;
            #pragma unroll
            for (int o = 0; o < 3; ++o) {
                muO[(size_t)(b*3+o)*NT + t] = 2.0f * fast_tanh(0.5f * hd[4+o]);
                const float sv = hd[7+o];
                sgO[(size_t)(b*3+o)*NT + t] = (sv > 15.0f) ? sv : logf(1.0f + __expf(sv));
            }
        }
        __syncthreads();
    }
}

extern "C" void kernel_launch(void* const* d_in, const int* in_sizes, int n_in,
                              void* d_out, int out_size, void* d_ws, size_t ws_size,
                              hipStream_t stream)
{
    const float* x     = (const float*)d_in[0];
    const float* w_in  = (const float*)d_in[1];
    const float* b_in  = (const float*)d_in[2];
    const float* bw1   = (const float*)d_in[3];   // [8][128][64][2]
    const float* bb1   = (const float*)d_in[4];   // [8][128]
    const float* bw2   = (const float*)d_in[5];   // [8][64][64][1]
    const float* bb2   = (const float*)d_in[6];   // [8][64]
    const float* w_mid = (const float*)d_in[7];
    const float* b_mid = (const float*)d_in[8];
    const float* w_pi  = (const float*)d_in[9];
    const float* b_pi  = (const float*)d_in[10];
    const float* w_mu  = (const float*)d_in[11];
    const float* b_mu  = (const float*)d_in[12];
    const float* w_sg  = (const float*)d_in[13];
    const float* b_sg  = (const float*)d_in[14];
    float* out = (float*)d_out;

    short* w1p = (short*)d_ws;                    // 262144 B
    short* w2p = w1p + 8*16384;                   // 65536 B
    float* wct = (float*)(w2p + 8*4096);          // 640 floats
    float* bcp = wct + 640;                       // 10 floats

    k_pack<<<80, 256, 0, stream>>>(bw1, bw2, w1p, w2p);
    k_compose<<<1, 1024, 0, stream>>>(w_mid, b_mid, w_pi, b_pi, w_mu, b_mu,
                                      w_sg, b_sg, wct, bcp);
    k_mega<<<dim3(NB, NT/TOUT), 512, 0, stream>>>(
        w1p, bb1, w2p, bb2, w_in, b_in, x, wct, bcp, out);
}